// Round 10
// baseline (2291.399 us; speedup 1.0000x reference)
//
#include <hip/hip_runtime.h>
#include <cmath>
#include <complex>
#include <vector>
#include <algorithm>

// ---------------- host-side CG generation (literal port of the numpy code) ----------------
namespace {

static double factd(int n) { double r = 1; for (int i = 2; i <= n; i++) r *= i; return r; }
static double par(int k) { return (k % 2 == 0) ? 1.0 : -1.0; }

static double w3j(int j1, int j2, int j3, int m1, int m2, int m3) {
    if (m1 + m2 + m3 != 0) return 0.0;
    if (j3 < std::abs(j1 - j2) || j3 > j1 + j2) return 0.0;
    int t1 = j2 - m1 - j3, t2 = j1 + m2 - j3;
    int t3 = j1 + j2 - j3, t4 = j1 - m1, t5 = j2 + m2;
    int lo = std::max(0, std::max(t1, t2)), hi = std::min(t3, std::min(t4, t5));
    double s = 0.0;
    for (int t = lo; t <= hi; t++)
        s += par(t) / (factd(t) * factd(t - t1) * factd(t - t2) *
                       factd(t3 - t) * factd(t4 - t) * factd(t5 - t));
    double n = par(j1 - j2 - m3)
        * std::sqrt(factd(j1 + j2 - j3) * factd(j1 - j2 + j3) * factd(-j1 + j2 + j3) / factd(j1 + j2 + j3 + 1))
        * std::sqrt(factd(j1 + m1) * factd(j1 - m1) * factd(j2 + m2) * factd(j2 - m2) * factd(j3 + m3) * factd(j3 - m3));
    return n * s;
}

static void Umat(int l, std::complex<double>* U) {
    int n = 2 * l + 1;
    for (int i = 0; i < n * n; i++) U[i] = 0.0;
    U[l * n + l] = 1.0;
    double s2 = 1.0 / std::sqrt(2.0);
    for (int m = 1; m <= l; m++) {
        U[(l + m) * n + (l + m)] = par(m) * s2;
        U[(l + m) * n + (l - m)] = s2;
        U[(l - m) * n + (l - m)] = std::complex<double>(0.0, s2);
        U[(l - m) * n + (l + m)] = std::complex<double>(0.0, -par(m) * s2);
    }
}

static void real_cg(int l1, int l2, int l3, float* out) {
    int n1 = 2 * l1 + 1, n2 = 2 * l2 + 1, n3 = 2 * l3 + 1;
    std::vector<std::complex<double>> Cc((size_t)n1 * n2 * n3, 0.0);
    for (int m1 = -l1; m1 <= l1; m1++)
        for (int m2 = -l2; m2 <= l2; m2++) {
            int m3 = m1 + m2;
            if (std::abs(m3) <= l3)
                Cc[((size_t)(l1 + m1) * n2 + (l2 + m2)) * n3 + (l3 + m3)] =
                    par(l1 - l2 + m3) * std::sqrt((double)(2 * l3 + 1)) * w3j(l1, l2, l3, m1, m2, -m3);
        }
    std::vector<std::complex<double>> U1((size_t)n1 * n1), U2((size_t)n2 * n2), U3((size_t)n3 * n3);
    Umat(l1, U1.data()); Umat(l2, U2.data()); Umat(l3, U3.data());
    std::vector<std::complex<double>> C((size_t)n1 * n2 * n3, 0.0);
    for (int a = 0; a < n1; a++)
        for (int b = 0; b < n2; b++)
            for (int c = 0; c < n3; c++) {
                std::complex<double> s = 0.0;
                for (int m = 0; m < n1; m++)
                    for (int nn = 0; nn < n2; nn++) {
                        std::complex<double> u12 = U1[(size_t)a * n1 + m] * U2[(size_t)b * n2 + nn];
                        if (u12 == std::complex<double>(0.0, 0.0)) continue;
                        for (int o = 0; o < n3; o++) {
                            std::complex<double> cc = Cc[((size_t)m * n2 + nn) * n3 + o];
                            if (cc == std::complex<double>(0.0, 0.0)) continue;
                            s += u12 * std::conj(U3[(size_t)c * n3 + o]) * cc;
                        }
                    }
                C[((size_t)a * n2 + b) * n3 + c] = s;
            }
    double sim = 0, sre = 0;
    for (auto& z : C) { sim += std::abs(z.imag()); sre += std::abs(z.real()); }
    std::vector<double> R(C.size());
    for (size_t i = 0; i < C.size(); i++) R[i] = (sim > sre) ? C[i].imag() : C[i].real();
    double ss = 0; for (double v : R) ss += v * v;
    double scale = std::sqrt((double)(2 * l3 + 1)) / std::sqrt(ss);
    for (size_t i = 0; i < R.size(); i++) out[i] = (float)(R[i] * scale);
}

}  // namespace

struct CGPack {
    float c000[1];  float c110[9];   float c220[25];
    float c011[9];  float c101[9];   float c121[45];  float c211[45]; float c321[105];
    float c022[25]; float c202[25];  float c222[125]; float c312[105];
    float c112[45]; float c123[105];
};

static void build_pack(CGPack& p) {
    real_cg(0, 0, 0, p.c000); real_cg(1, 1, 0, p.c110); real_cg(2, 2, 0, p.c220);
    real_cg(0, 1, 1, p.c011); real_cg(1, 0, 1, p.c101); real_cg(1, 2, 1, p.c121);
    real_cg(2, 1, 1, p.c211); real_cg(3, 2, 1, p.c321);
    real_cg(0, 2, 2, p.c022); real_cg(2, 0, 2, p.c202); real_cg(2, 2, 2, p.c222);
    real_cg(3, 1, 2, p.c312); real_cg(1, 1, 2, p.c112); real_cg(1, 2, 3, p.c123);
}

// ---------------- device helpers ----------------

template <int NA, int NB, int NC>
__device__ __forceinline__ void tpc(const float* __restrict__ C,
                                    const float* __restrict__ a,
                                    const float* __restrict__ b,
                                    float* __restrict__ out) {
#pragma unroll
    for (int c = 0; c < NC; c++) {
        float s = 0.f;
#pragma unroll
        for (int i = 0; i < NA; i++) {
#pragma unroll
            for (int j = 0; j < NB; j++)
                s += C[(i * NB + j) * NC + c] * a[i] * b[j];
        }
        out[c] = s;
    }
}

// strided-output variant: out[c*ST]
template <int NA, int NB, int NC, int ST>
__device__ __forceinline__ void tpcs(const float* __restrict__ C,
                                     const float* __restrict__ a,
                                     const float* __restrict__ b,
                                     float* __restrict__ out) {
#pragma unroll
    for (int c = 0; c < NC; c++) {
        float s = 0.f;
#pragma unroll
        for (int i = 0; i < NA; i++) {
#pragma unroll
            for (int j = 0; j < NB; j++)
                s += C[(i * NB + j) * NC + c] * a[i] * b[j];
        }
        out[c * ST] = s;
    }
}

__device__ __forceinline__ float silu(float v) { return v / (1.f + expf(-v)); }
__device__ __forceinline__ float dot4(float4 a, float4 b) {
    return a.x * b.x + a.y * b.y + a.z * b.z + a.w * b.w;
}

#define EPSC 0.1f
#define INV_SQRT128 0.08838834764831845f
#define INV_SQRT320 0.05590169943749474f
#define SQRT5 2.2360679774997896f
#define SQRT7 2.6457513110645907f
#define SQRT3 1.7320508075688772f

// pack-region sizes (in float4 elements)
#define N_WVQ  (160 * 64)
#define N_W2A  (80 * 64)
#define N_W2B  (16 * 64)
#define N_W2C  (16 * 64)
#define N_W1I  (32 * 64)

// ---------------- kernel P: pre-pack weights into wide-load layouts ----------------
__global__ __launch_bounds__(256) void k_pack(
    const float* __restrict__ Wv1, const float* __restrict__ Wv2,
    const float* __restrict__ W2a, const float* __restrict__ W2b, const float* __restrict__ W2c,
    const float* __restrict__ W1,
    float4* __restrict__ WvQ, float4* __restrict__ W2aI,
    float4* __restrict__ W2bI, float4* __restrict__ W2cI, float4* __restrict__ W1I) {
    int i = blockIdx.x * blockDim.x + threadIdx.x;
    if (i < N_WVQ) {
        int t2 = i >> 6, u = i & 63;
        WvQ[i] = make_float4(Wv1[(2 * t2) * 64 + u], Wv2[(2 * t2) * 64 + u],
                             Wv1[(2 * t2 + 1) * 64 + u], Wv2[(2 * t2 + 1) * 64 + u]);
    } else if (i < N_WVQ + N_W2A) {
        int j = i - N_WVQ; int g = j >> 6, u = j & 63;
        W2aI[j] = make_float4(W2a[(4 * g) * 64 + u], W2a[(4 * g + 1) * 64 + u],
                              W2a[(4 * g + 2) * 64 + u], W2a[(4 * g + 3) * 64 + u]);
    } else if (i < N_WVQ + N_W2A + N_W2B) {
        int j = i - N_WVQ - N_W2A; int g = j >> 6, u = j & 63;
        W2bI[j] = make_float4(W2b[(4 * g) * 64 + u], W2b[(4 * g + 1) * 64 + u],
                              W2b[(4 * g + 2) * 64 + u], W2b[(4 * g + 3) * 64 + u]);
    } else if (i < N_WVQ + N_W2A + N_W2B + N_W2C) {
        int j = i - N_WVQ - N_W2A - N_W2B; int g = j >> 6, u = j & 63;
        W2cI[j] = make_float4(W2c[(4 * g) * 64 + u], W2c[(4 * g + 1) * 64 + u],
                              W2c[(4 * g + 2) * 64 + u], W2c[(4 * g + 3) * 64 + u]);
    } else if (i < N_WVQ + N_W2A + N_W2B + N_W2C + N_W1I) {
        int j = i - N_WVQ - N_W2A - N_W2B - N_W2C; int g = j >> 6, u = j & 63;
        W1I[j] = make_float4(W1[(4 * g) * 64 + u], W1[(4 * g + 1) * 64 + u],
                             W1[(4 * g + 2) * 64 + u], W1[(4 * g + 3) * 64 + u]);
    }
}

// ---------------- kernel A: Y + w, scatter-add into node[n][64][16] (k inner!) ----------------
__global__ __launch_bounds__(256) void k_edge_pre(
    const float* __restrict__ vectors, const float* __restrict__ x,
    const int* __restrict__ senders, const float4* __restrict__ W1I,
    float* __restrict__ node, int E, CGPack cg) {
    int wid = (blockIdx.x * blockDim.x + threadIdx.x) >> 6;
    int lane = threadIdx.x & 63;
    if (wid >= E) return;
    int e = wid;
    float vx = vectors[e * 3 + 0], vy = vectors[e * 3 + 1], vz = vectors[e * 3 + 2];
    float inv = rsqrtf(vx * vx + vy * vy + vz * vz);
    float ux = vx * inv, uy = vy * inv, uz = vz * inv;

    float Y[16];
    Y[0] = 1.f;
    float y1[3] = { SQRT3 * uy, SQRT3 * uz, SQRT3 * ux };
    float t2[5]; tpc<3, 3, 5>(cg.c112, y1, y1, t2);
    float n2 = 0.f;
#pragma unroll
    for (int c = 0; c < 5; c++) n2 += t2[c] * t2[c];
    float sc2 = SQRT5 * rsqrtf(n2);
    float y2[5];
#pragma unroll
    for (int c = 0; c < 5; c++) y2[c] = t2[c] * sc2;
    float t3[7]; tpc<3, 5, 7>(cg.c123, y1, y2, t3);
    float n3 = 0.f;
#pragma unroll
    for (int c = 0; c < 7; c++) n3 += t3[c] * t3[c];
    float sc3 = SQRT7 * rsqrtf(n3);
#pragma unroll
    for (int j = 0; j < 3; j++) Y[1 + j] = y1[j];
#pragma unroll
    for (int j = 0; j < 5; j++) Y[4 + j] = y2[j];
#pragma unroll
    for (int j = 0; j < 7; j++) Y[9 + j] = t3[j] * sc3;

    // w[lane] = (x[e] . W1[:,lane]) / sqrt(128), float4-packed weights
    const float4* xr4 = (const float4*)(x + (size_t)e * 128);
    float w = 0.f;
#pragma unroll 8
    for (int g = 0; g < 32; g++) w += dot4(xr4[g], W1I[g * 64 + lane]);
    w *= INV_SQRT128;

    int s = senders[e];
    float* nb = node + (size_t)s * 1024 + lane * 16;   // [n][u][k], k contiguous
#pragma unroll
    for (int k = 0; k < 16; k++) atomicAdd(nb + k, w * Y[k]);
}

// ---------------- kernel B: gather, tensor products, MLP, Wv contractions ----------------
__global__ __launch_bounds__(64, 4) void k_edge_main(
    const float* __restrict__ vectors, const float* __restrict__ x,
    const float* __restrict__ V, const int* __restrict__ senders,
    const float* __restrict__ node, const float4* __restrict__ WvQ,
    const float4* __restrict__ W2aI, const float4* __restrict__ W2bI, const float4* __restrict__ W2cI,
    float* __restrict__ xout, float* __restrict__ vout, int E, CGPack cg) {
    __shared__ __align__(16) float V1sh[3][320];
    __shared__ __align__(16) float V2sh[5][320];
    __shared__ __align__(16) float Ssh[192];
    __shared__ __align__(16) float Hsh[64];

    int e = blockIdx.x;
    int u = threadIdx.x;
    int s = senders[e];

    // gather A = node[s][u][0..15] * eps  (4 x dwordx4, coalesced)
    const float4* nb4 = (const float4*)(node + (size_t)s * 1024 + u * 16);
    float4 g0 = nb4[0], g1 = nb4[1], g2 = nb4[2], g3 = nb4[3];
    float a0 = g0.x * EPSC;
    float a1[3] = { g0.y * EPSC, g0.z * EPSC, g0.w * EPSC };
    float a2[5] = { g1.x * EPSC, g1.y * EPSC, g1.z * EPSC, g1.w * EPSC, g2.x * EPSC };
    float a3[7] = { g2.y * EPSC, g2.z * EPSC, g2.w * EPSC, g3.x * EPSC,
                    g3.y * EPSC, g3.z * EPSC, g3.w * EPSC };

    // B = V[e,u,:]  (0e | 1o | 2e)
    const float* vb = V + (size_t)e * 576 + u * 9;
    float b0 = vb[0];
    float b1[3] = { vb[1], vb[2], vb[3] };
    float b2[5] = { vb[4], vb[5], vb[6], vb[7], vb[8] };

    // ---- S (l3=0) ----
    {
        float o[1];
        Ssh[u * 3 + 0] = cg.c000[0] * a0 * b0;
        tpc<3, 3, 1>(cg.c110, a1, b1, o); Ssh[u * 3 + 1] = o[0];
        tpc<5, 5, 1>(cg.c220, a2, b2, o); Ssh[u * 3 + 2] = o[0];
    }
    // ---- V1 (l3=1): p=0..4 at t=u*5+p, component-major [c][t] ----
    {
        float* v1 = &V1sh[0][u * 5];
        tpcs<1, 3, 3, 320>(cg.c011, &a0, b1, v1 + 0);
        tpcs<3, 1, 3, 320>(cg.c101, a1, &b0, v1 + 1);
        tpcs<3, 5, 3, 320>(cg.c121, a1, b2, v1 + 2);
        tpcs<5, 3, 3, 320>(cg.c211, a2, b1, v1 + 3);
        tpcs<7, 5, 3, 320>(cg.c321, a3, b2, v1 + 4);
    }
    // ---- V2 (l3=2): p=0..4 at t=u*5+p, component-major [c][t] ----
    {
        float* v2 = &V2sh[0][u * 5];
        tpcs<1, 5, 5, 320>(cg.c022, &a0, b2, v2 + 0);
        tpcs<3, 3, 5, 320>(cg.c112, a1, b1, v2 + 1);
        tpcs<5, 1, 5, 320>(cg.c202, a2, &b0, v2 + 2);
        tpcs<5, 5, 5, 320>(cg.c222, a2, b2, v2 + 3);
        tpcs<7, 3, 5, 320>(cg.c312, a3, b1, v2 + 4);
    }
    __syncthreads();

    // ---- MLP layer 1: x2 = [x (128), S (192)] -> 64, all float4 loads ----
    const float4* xr4 = (const float4*)(x + (size_t)e * 128);
    float h = 0.f;
#pragma unroll 8
    for (int g = 0; g < 32; g++) h += dot4(xr4[g], W2aI[g * 64 + u]);
    const float4* S4 = (const float4*)Ssh;
#pragma unroll 8
    for (int g = 0; g < 48; g++) h += dot4(S4[g], W2aI[(32 + g) * 64 + u]);
    h = silu(h * INV_SQRT320);
    Hsh[u] = h;
    __syncthreads();
    const float4* H4 = (const float4*)Hsh;
    float h2 = 0.f;
#pragma unroll 8
    for (int g = 0; g < 16; g++) h2 += dot4(H4[g], W2bI[g * 64 + u]);
    h2 = silu(h2 * 0.125f);
    __syncthreads();
    Hsh[u] = h2;
    __syncthreads();
    float h3 = 0.f;
#pragma unroll 8
    for (int g = 0; g < 16; g++) h3 += dot4(H4[g], W2cI[g * 64 + u]);
    h3 *= 0.125f;

    // envelope(len)
    float vx = vectors[e * 3 + 0], vy = vectors[e * 3 + 1], vz = vectors[e * 3 + 2];
    float len = sqrtf(vx * vx + vy * vy + vz * vz);
    float d2 = len * len, d4 = d2 * d2, d6 = d4 * d2, d7 = d6 * len, d8 = d7 * len;
    float env = 1.f - 28.f * d6 + 48.f * d7 - 21.f * d8;
    if (!(len < 1.f)) env = 0.f;
    xout[(size_t)e * 64 + u] = env * h3;

    // ---- fused Wv contractions: out[u][c] = sum_t V[c][t] * Wv[t,u] ----
    // WvQ[t2*64+u] = {Wv1[2t2,u], Wv2[2t2,u], Wv1[2t2+1,u], Wv2[2t2+1,u]}
    float acc1[3] = { 0.f, 0.f, 0.f };
    float acc2[5] = { 0.f, 0.f, 0.f, 0.f, 0.f };
    const float4* wvp = WvQ + u;
    for (int t4 = 0; t4 < 80; ++t4) {
        float4 wq0 = wvp[(2 * t4) * 64];       // t+0, t+1
        float4 wq1 = wvp[(2 * t4 + 1) * 64];   // t+2, t+3
        int t = t4 * 4;
#pragma unroll
        for (int c = 0; c < 3; c++) {
            float4 v = *(const float4*)&V1sh[c][t];
            acc1[c] += v.x * wq0.x + v.y * wq0.z + v.z * wq1.x + v.w * wq1.z;
        }
#pragma unroll
        for (int c = 0; c < 5; c++) {
            float4 v = *(const float4*)&V2sh[c][t];
            acc2[c] += v.x * wq0.y + v.y * wq0.w + v.z * wq1.y + v.w * wq1.w;
        }
    }
    float* vo = vout + (size_t)e * 512;
#pragma unroll
    for (int c = 0; c < 3; c++) vo[u * 3 + c] = acc1[c] * INV_SQRT320;
#pragma unroll
    for (int c = 0; c < 5; c++) vo[192 + u * 5 + c] = acc2[c] * INV_SQRT320;
}

// ---------------- launch ----------------
extern "C" void kernel_launch(void* const* d_in, const int* in_sizes, int n_in,
                              void* d_out, int out_size, void* d_ws, size_t ws_size,
                              hipStream_t stream) {
    const float* vectors = (const float*)d_in[0];
    const float* x       = (const float*)d_in[1];
    const float* V       = (const float*)d_in[2];
    const int*   senders = (const int*)d_in[3];
    // d_in[4] = species (unused by layer body)
    const float* W1  = (const float*)d_in[5];
    const float* W2a = (const float*)d_in[6];
    const float* W2b = (const float*)d_in[7];
    const float* W2c = (const float*)d_in[8];
    const float* Wv1 = (const float*)d_in[9];
    const float* Wv2 = (const float*)d_in[10];

    int E = in_sizes[0] / 3;
    int N = in_sizes[4];

    CGPack pack;
    build_pack(pack);

    // workspace layout
    char* wp = (char*)d_ws;
    float*  node = (float*)wp;                 wp += (size_t)N * 1024 * sizeof(float);  // 8 MB
    float4* WvQ  = (float4*)wp;                wp += (size_t)N_WVQ * sizeof(float4);    // 160 KB
    float4* W2aI = (float4*)wp;                wp += (size_t)N_W2A * sizeof(float4);    // 80 KB
    float4* W2bI = (float4*)wp;                wp += (size_t)N_W2B * sizeof(float4);    // 16 KB
    float4* W2cI = (float4*)wp;                wp += (size_t)N_W2C * sizeof(float4);    // 16 KB
    float4* W1I  = (float4*)wp;                wp += (size_t)N_W1I * sizeof(float4);    // 32 KB

    hipMemsetAsync(node, 0, (size_t)N * 1024 * sizeof(float), stream);

    int npack = N_WVQ + N_W2A + N_W2B + N_W2C + N_W1I;
    hipLaunchKernelGGL(k_pack, dim3((npack + 255) / 256), dim3(256), 0, stream,
                       Wv1, Wv2, W2a, W2b, W2c, W1, WvQ, W2aI, W2bI, W2cI, W1I);

    dim3 blkA(256), grdA((unsigned)(((size_t)E * 64 + 255) / 256));
    hipLaunchKernelGGL(k_edge_pre, grdA, blkA, 0, stream,
                       vectors, x, senders, W1I, node, E, pack);

    float* xout = (float*)d_out;
    float* vout = xout + (size_t)E * 64;
    hipLaunchKernelGGL(k_edge_main, dim3((unsigned)E), dim3(64), 0, stream,
                       vectors, x, V, senders, node, WvQ,
                       W2aI, W2bI, W2cI, xout, vout, E, pack);
}

// Round 11
// 663.254 us; speedup vs baseline: 3.4548x; 3.4548x over previous
//
#include <hip/hip_runtime.h>
#include <cmath>
#include <complex>
#include <vector>
#include <algorithm>

// ---------------- host-side CG generation (literal port of the numpy code) ----------------
namespace {

static double factd(int n) { double r = 1; for (int i = 2; i <= n; i++) r *= i; return r; }
static double par(int k) { return (k % 2 == 0) ? 1.0 : -1.0; }

static double w3j(int j1, int j2, int j3, int m1, int m2, int m3) {
    if (m1 + m2 + m3 != 0) return 0.0;
    if (j3 < std::abs(j1 - j2) || j3 > j1 + j2) return 0.0;
    int t1 = j2 - m1 - j3, t2 = j1 + m2 - j3;
    int t3 = j1 + j2 - j3, t4 = j1 - m1, t5 = j2 + m2;
    int lo = std::max(0, std::max(t1, t2)), hi = std::min(t3, std::min(t4, t5));
    double s = 0.0;
    for (int t = lo; t <= hi; t++)
        s += par(t) / (factd(t) * factd(t - t1) * factd(t - t2) *
                       factd(t3 - t) * factd(t4 - t) * factd(t5 - t));
    double n = par(j1 - j2 - m3)
        * std::sqrt(factd(j1 + j2 - j3) * factd(j1 - j2 + j3) * factd(-j1 + j2 + j3) / factd(j1 + j2 + j3 + 1))
        * std::sqrt(factd(j1 + m1) * factd(j1 - m1) * factd(j2 + m2) * factd(j2 - m2) * factd(j3 + m3) * factd(j3 - m3));
    return n * s;
}

static void Umat(int l, std::complex<double>* U) {
    int n = 2 * l + 1;
    for (int i = 0; i < n * n; i++) U[i] = 0.0;
    U[l * n + l] = 1.0;
    double s2 = 1.0 / std::sqrt(2.0);
    for (int m = 1; m <= l; m++) {
        U[(l + m) * n + (l + m)] = par(m) * s2;
        U[(l + m) * n + (l - m)] = s2;
        U[(l - m) * n + (l - m)] = std::complex<double>(0.0, s2);
        U[(l - m) * n + (l + m)] = std::complex<double>(0.0, -par(m) * s2);
    }
}

static void real_cg(int l1, int l2, int l3, float* out) {
    int n1 = 2 * l1 + 1, n2 = 2 * l2 + 1, n3 = 2 * l3 + 1;
    std::vector<std::complex<double>> Cc((size_t)n1 * n2 * n3, 0.0);
    for (int m1 = -l1; m1 <= l1; m1++)
        for (int m2 = -l2; m2 <= l2; m2++) {
            int m3 = m1 + m2;
            if (std::abs(m3) <= l3)
                Cc[((size_t)(l1 + m1) * n2 + (l2 + m2)) * n3 + (l3 + m3)] =
                    par(l1 - l2 + m3) * std::sqrt((double)(2 * l3 + 1)) * w3j(l1, l2, l3, m1, m2, -m3);
        }
    std::vector<std::complex<double>> U1((size_t)n1 * n1), U2((size_t)n2 * n2), U3((size_t)n3 * n3);
    Umat(l1, U1.data()); Umat(l2, U2.data()); Umat(l3, U3.data());
    std::vector<std::complex<double>> C((size_t)n1 * n2 * n3, 0.0);
    for (int a = 0; a < n1; a++)
        for (int b = 0; b < n2; b++)
            for (int c = 0; c < n3; c++) {
                std::complex<double> s = 0.0;
                for (int m = 0; m < n1; m++)
                    for (int nn = 0; nn < n2; nn++) {
                        std::complex<double> u12 = U1[(size_t)a * n1 + m] * U2[(size_t)b * n2 + nn];
                        if (u12 == std::complex<double>(0.0, 0.0)) continue;
                        for (int o = 0; o < n3; o++) {
                            std::complex<double> cc = Cc[((size_t)m * n2 + nn) * n3 + o];
                            if (cc == std::complex<double>(0.0, 0.0)) continue;
                            s += u12 * std::conj(U3[(size_t)c * n3 + o]) * cc;
                        }
                    }
                C[((size_t)a * n2 + b) * n3 + c] = s;
            }
    double sim = 0, sre = 0;
    for (auto& z : C) { sim += std::abs(z.imag()); sre += std::abs(z.real()); }
    std::vector<double> R(C.size());
    for (size_t i = 0; i < C.size(); i++) R[i] = (sim > sre) ? C[i].imag() : C[i].real();
    double ss = 0; for (double v : R) ss += v * v;
    double scale = std::sqrt((double)(2 * l3 + 1)) / std::sqrt(ss);
    for (size_t i = 0; i < R.size(); i++) out[i] = (float)(R[i] * scale);
}

}  // namespace

struct CGPack {
    float c000[1];  float c110[9];   float c220[25];
    float c011[9];  float c101[9];   float c121[45];  float c211[45]; float c321[105];
    float c022[25]; float c202[25];  float c222[125]; float c312[105];
    float c112[45]; float c123[105];
};

static void build_pack(CGPack& p) {
    real_cg(0, 0, 0, p.c000); real_cg(1, 1, 0, p.c110); real_cg(2, 2, 0, p.c220);
    real_cg(0, 1, 1, p.c011); real_cg(1, 0, 1, p.c101); real_cg(1, 2, 1, p.c121);
    real_cg(2, 1, 1, p.c211); real_cg(3, 2, 1, p.c321);
    real_cg(0, 2, 2, p.c022); real_cg(2, 0, 2, p.c202); real_cg(2, 2, 2, p.c222);
    real_cg(3, 1, 2, p.c312); real_cg(1, 1, 2, p.c112); real_cg(1, 2, 3, p.c123);
}

// ---------------- device helpers ----------------

template <int NA, int NB, int NC>
__device__ __forceinline__ void tpc(const float* __restrict__ C,
                                    const float* __restrict__ a,
                                    const float* __restrict__ b,
                                    float* __restrict__ out) {
#pragma unroll
    for (int c = 0; c < NC; c++) {
        float s = 0.f;
#pragma unroll
        for (int i = 0; i < NA; i++) {
#pragma unroll
            for (int j = 0; j < NB; j++)
                s += C[(i * NB + j) * NC + c] * a[i] * b[j];
        }
        out[c] = s;
    }
}

// strided-output variant: out[c*ST]
template <int NA, int NB, int NC, int ST>
__device__ __forceinline__ void tpcs(const float* __restrict__ C,
                                     const float* __restrict__ a,
                                     const float* __restrict__ b,
                                     float* __restrict__ out) {
#pragma unroll
    for (int c = 0; c < NC; c++) {
        float s = 0.f;
#pragma unroll
        for (int i = 0; i < NA; i++) {
#pragma unroll
            for (int j = 0; j < NB; j++)
                s += C[(i * NB + j) * NC + c] * a[i] * b[j];
        }
        out[c * ST] = s;
    }
}

__device__ __forceinline__ float silu(float v) { return v / (1.f + expf(-v)); }
__device__ __forceinline__ float dot4(float4 a, float4 b) {
    return a.x * b.x + a.y * b.y + a.z * b.z + a.w * b.w;
}

#define EPSC 0.1f
#define INV_SQRT128 0.08838834764831845f
#define INV_SQRT320 0.05590169943749474f
#define SQRT5 2.2360679774997896f
#define SQRT7 2.6457513110645907f
#define SQRT3 1.7320508075688772f

// pack-region sizes (in float4 elements)
#define N_WVQ  (160 * 64)
#define N_W2A  (80 * 64)
#define N_W2B  (16 * 64)
#define N_W2C  (16 * 64)
#define N_W1I  (32 * 64)

// ---------------- kernel P: pre-pack weights into wide-load layouts ----------------
__global__ __launch_bounds__(256) void k_pack(
    const float* __restrict__ Wv1, const float* __restrict__ Wv2,
    const float* __restrict__ W2a, const float* __restrict__ W2b, const float* __restrict__ W2c,
    const float* __restrict__ W1,
    float4* __restrict__ WvQ, float4* __restrict__ W2aI,
    float4* __restrict__ W2bI, float4* __restrict__ W2cI, float4* __restrict__ W1I) {
    int i = blockIdx.x * blockDim.x + threadIdx.x;
    if (i < N_WVQ) {
        int t2 = i >> 6, u = i & 63;
        WvQ[i] = make_float4(Wv1[(2 * t2) * 64 + u], Wv2[(2 * t2) * 64 + u],
                             Wv1[(2 * t2 + 1) * 64 + u], Wv2[(2 * t2 + 1) * 64 + u]);
    } else if (i < N_WVQ + N_W2A) {
        int j = i - N_WVQ; int g = j >> 6, u = j & 63;
        W2aI[j] = make_float4(W2a[(4 * g) * 64 + u], W2a[(4 * g + 1) * 64 + u],
                              W2a[(4 * g + 2) * 64 + u], W2a[(4 * g + 3) * 64 + u]);
    } else if (i < N_WVQ + N_W2A + N_W2B) {
        int j = i - N_WVQ - N_W2A; int g = j >> 6, u = j & 63;
        W2bI[j] = make_float4(W2b[(4 * g) * 64 + u], W2b[(4 * g + 1) * 64 + u],
                              W2b[(4 * g + 2) * 64 + u], W2b[(4 * g + 3) * 64 + u]);
    } else if (i < N_WVQ + N_W2A + N_W2B + N_W2C) {
        int j = i - N_WVQ - N_W2A - N_W2B; int g = j >> 6, u = j & 63;
        W2cI[j] = make_float4(W2c[(4 * g) * 64 + u], W2c[(4 * g + 1) * 64 + u],
                              W2c[(4 * g + 2) * 64 + u], W2c[(4 * g + 3) * 64 + u]);
    } else if (i < N_WVQ + N_W2A + N_W2B + N_W2C + N_W1I) {
        int j = i - N_WVQ - N_W2A - N_W2B - N_W2C; int g = j >> 6, u = j & 63;
        W1I[j] = make_float4(W1[(4 * g) * 64 + u], W1[(4 * g + 1) * 64 + u],
                             W1[(4 * g + 2) * 64 + u], W1[(4 * g + 3) * 64 + u]);
    }
}

// ---------------- kernel A: Y + w, scatter-add into node[n][16][64] (lane-coalesced atomics) ----------------
__global__ __launch_bounds__(256) void k_edge_pre(
    const float* __restrict__ vectors, const float* __restrict__ x,
    const int* __restrict__ senders, const float4* __restrict__ W1I,
    float* __restrict__ node, int E, CGPack cg) {
    int wid = (blockIdx.x * blockDim.x + threadIdx.x) >> 6;
    int lane = threadIdx.x & 63;
    if (wid >= E) return;
    int e = wid;
    float vx = vectors[e * 3 + 0], vy = vectors[e * 3 + 1], vz = vectors[e * 3 + 2];
    float inv = rsqrtf(vx * vx + vy * vy + vz * vz);
    float ux = vx * inv, uy = vy * inv, uz = vz * inv;

    float Y[16];
    Y[0] = 1.f;
    float y1[3] = { SQRT3 * uy, SQRT3 * uz, SQRT3 * ux };
    float t2[5]; tpc<3, 3, 5>(cg.c112, y1, y1, t2);
    float n2 = 0.f;
#pragma unroll
    for (int c = 0; c < 5; c++) n2 += t2[c] * t2[c];
    float sc2 = SQRT5 * rsqrtf(n2);
    float y2[5];
#pragma unroll
    for (int c = 0; c < 5; c++) y2[c] = t2[c] * sc2;
    float t3[7]; tpc<3, 5, 7>(cg.c123, y1, y2, t3);
    float n3 = 0.f;
#pragma unroll
    for (int c = 0; c < 7; c++) n3 += t3[c] * t3[c];
    float sc3 = SQRT7 * rsqrtf(n3);
#pragma unroll
    for (int j = 0; j < 3; j++) Y[1 + j] = y1[j];
#pragma unroll
    for (int j = 0; j < 5; j++) Y[4 + j] = y2[j];
#pragma unroll
    for (int j = 0; j < 7; j++) Y[9 + j] = t3[j] * sc3;

    // w[lane] = (x[e] . W1[:,lane]) / sqrt(128), float4-packed weights
    const float4* xr4 = (const float4*)(x + (size_t)e * 128);
    float w = 0.f;
#pragma unroll 8
    for (int g = 0; g < 32; g++) w += dot4(xr4[g], W1I[g * 64 + lane]);
    w *= INV_SQRT128;

    int s = senders[e];
    float* nb = node + (size_t)s * 1024 + lane;   // [n][k][u], u contiguous across lanes
#pragma unroll
    for (int k = 0; k < 16; k++) atomicAdd(nb + k * 64, w * Y[k]);
}

// ---------------- kernel B: gather, tensor products, MLP, Wv contractions ----------------
__global__ __launch_bounds__(64, 4) void k_edge_main(
    const float* __restrict__ vectors, const float* __restrict__ x,
    const float* __restrict__ V, const int* __restrict__ senders,
    const float* __restrict__ node, const float4* __restrict__ WvQ,
    const float4* __restrict__ W2aI, const float4* __restrict__ W2bI, const float4* __restrict__ W2cI,
    float* __restrict__ xout, float* __restrict__ vout, int E, CGPack cg) {
    __shared__ __align__(16) float V1sh[3][320];
    __shared__ __align__(16) float V2sh[5][320];
    __shared__ __align__(16) float Ssh[192];
    __shared__ __align__(16) float Hsh[64];

    int e = blockIdx.x;
    int u = threadIdx.x;
    int s = senders[e];

    // gather A = node[s][k][u] * eps  (16 loads, lane-coalesced per k)
    const float* nb = node + (size_t)s * 1024 + u;
    float a0 = nb[0] * EPSC;
    float a1[3], a2[5], a3[7];
#pragma unroll
    for (int j = 0; j < 3; j++) a1[j] = nb[(1 + j) * 64] * EPSC;
#pragma unroll
    for (int j = 0; j < 5; j++) a2[j] = nb[(4 + j) * 64] * EPSC;
#pragma unroll
    for (int j = 0; j < 7; j++) a3[j] = nb[(9 + j) * 64] * EPSC;

    // B = V[e,u,:]  (0e | 1o | 2e)
    const float* vb = V + (size_t)e * 576 + u * 9;
    float b0 = vb[0];
    float b1[3] = { vb[1], vb[2], vb[3] };
    float b2[5] = { vb[4], vb[5], vb[6], vb[7], vb[8] };

    // ---- S (l3=0) ----
    {
        float o[1];
        Ssh[u * 3 + 0] = cg.c000[0] * a0 * b0;
        tpc<3, 3, 1>(cg.c110, a1, b1, o); Ssh[u * 3 + 1] = o[0];
        tpc<5, 5, 1>(cg.c220, a2, b2, o); Ssh[u * 3 + 2] = o[0];
    }
    // ---- V1 (l3=1): p=0..4 at t=u*5+p, component-major [c][t] ----
    {
        float* v1 = &V1sh[0][u * 5];
        tpcs<1, 3, 3, 320>(cg.c011, &a0, b1, v1 + 0);
        tpcs<3, 1, 3, 320>(cg.c101, a1, &b0, v1 + 1);
        tpcs<3, 5, 3, 320>(cg.c121, a1, b2, v1 + 2);
        tpcs<5, 3, 3, 320>(cg.c211, a2, b1, v1 + 3);
        tpcs<7, 5, 3, 320>(cg.c321, a3, b2, v1 + 4);
    }
    // ---- V2 (l3=2): p=0..4 at t=u*5+p, component-major [c][t] ----
    {
        float* v2 = &V2sh[0][u * 5];
        tpcs<1, 5, 5, 320>(cg.c022, &a0, b2, v2 + 0);
        tpcs<3, 3, 5, 320>(cg.c112, a1, b1, v2 + 1);
        tpcs<5, 1, 5, 320>(cg.c202, a2, &b0, v2 + 2);
        tpcs<5, 5, 5, 320>(cg.c222, a2, b2, v2 + 3);
        tpcs<7, 3, 5, 320>(cg.c312, a3, b1, v2 + 4);
    }
    __syncthreads();

    // ---- MLP layer 1: x2 = [x (128), S (192)] -> 64, all float4 loads ----
    const float4* xr4 = (const float4*)(x + (size_t)e * 128);
    float h = 0.f;
#pragma unroll 8
    for (int g = 0; g < 32; g++) h += dot4(xr4[g], W2aI[g * 64 + u]);
    const float4* S4 = (const float4*)Ssh;
#pragma unroll 8
    for (int g = 0; g < 48; g++) h += dot4(S4[g], W2aI[(32 + g) * 64 + u]);
    h = silu(h * INV_SQRT320);
    Hsh[u] = h;
    __syncthreads();
    const float4* H4 = (const float4*)Hsh;
    float h2 = 0.f;
#pragma unroll 8
    for (int g = 0; g < 16; g++) h2 += dot4(H4[g], W2bI[g * 64 + u]);
    h2 = silu(h2 * 0.125f);
    __syncthreads();
    Hsh[u] = h2;
    __syncthreads();
    float h3 = 0.f;
#pragma unroll 8
    for (int g = 0; g < 16; g++) h3 += dot4(H4[g], W2cI[g * 64 + u]);
    h3 *= 0.125f;

    // envelope(len)
    float vx = vectors[e * 3 + 0], vy = vectors[e * 3 + 1], vz = vectors[e * 3 + 2];
    float len = sqrtf(vx * vx + vy * vy + vz * vz);
    float d2 = len * len, d4 = d2 * d2, d6 = d4 * d2, d7 = d6 * len, d8 = d7 * len;
    float env = 1.f - 28.f * d6 + 48.f * d7 - 21.f * d8;
    if (!(len < 1.f)) env = 0.f;
    xout[(size_t)e * 64 + u] = env * h3;

    // ---- fused Wv contractions: out[u][c] = sum_t V[c][t] * Wv[t,u] ----
    // WvQ[t2*64+u] = {Wv1[2t2,u], Wv2[2t2,u], Wv1[2t2+1,u], Wv2[2t2+1,u]}
    float acc1[3] = { 0.f, 0.f, 0.f };
    float acc2[5] = { 0.f, 0.f, 0.f, 0.f, 0.f };
    const float4* wvp = WvQ + u;
    for (int t4 = 0; t4 < 80; ++t4) {
        float4 wq0 = wvp[(2 * t4) * 64];       // t+0, t+1
        float4 wq1 = wvp[(2 * t4 + 1) * 64];   // t+2, t+3
        int t = t4 * 4;
#pragma unroll
        for (int c = 0; c < 3; c++) {
            float4 v = *(const float4*)&V1sh[c][t];
            acc1[c] += v.x * wq0.x + v.y * wq0.z + v.z * wq1.x + v.w * wq1.z;
        }
#pragma unroll
        for (int c = 0; c < 5; c++) {
            float4 v = *(const float4*)&V2sh[c][t];
            acc2[c] += v.x * wq0.y + v.y * wq0.w + v.z * wq1.y + v.w * wq1.w;
        }
    }
    float* vo = vout + (size_t)e * 512;
#pragma unroll
    for (int c = 0; c < 3; c++) vo[u * 3 + c] = acc1[c] * INV_SQRT320;
#pragma unroll
    for (int c = 0; c < 5; c++) vo[192 + u * 5 + c] = acc2[c] * INV_SQRT320;
}

// ---------------- launch ----------------
extern "C" void kernel_launch(void* const* d_in, const int* in_sizes, int n_in,
                              void* d_out, int out_size, void* d_ws, size_t ws_size,
                              hipStream_t stream) {
    const float* vectors = (const float*)d_in[0];
    const float* x       = (const float*)d_in[1];
    const float* V       = (const float*)d_in[2];
    const int*   senders = (const int*)d_in[3];
    // d_in[4] = species (unused by layer body)
    const float* W1  = (const float*)d_in[5];
    const float* W2a = (const float*)d_in[6];
    const float* W2b = (const float*)d_in[7];
    const float* W2c = (const float*)d_in[8];
    const float* Wv1 = (const float*)d_in[9];
    const float* Wv2 = (const float*)d_in[10];

    int E = in_sizes[0] / 3;
    int N = in_sizes[4];

    CGPack pack;
    build_pack(pack);

    // workspace layout
    char* wp = (char*)d_ws;
    float*  node = (float*)wp;                 wp += (size_t)N * 1024 * sizeof(float);  // 8 MB
    float4* WvQ  = (float4*)wp;                wp += (size_t)N_WVQ * sizeof(float4);    // 160 KB
    float4* W2aI = (float4*)wp;                wp += (size_t)N_W2A * sizeof(float4);    // 80 KB
    float4* W2bI = (float4*)wp;                wp += (size_t)N_W2B * sizeof(float4);    // 16 KB
    float4* W2cI = (float4*)wp;                wp += (size_t)N_W2C * sizeof(float4);    // 16 KB
    float4* W1I  = (float4*)wp;                wp += (size_t)N_W1I * sizeof(float4);    // 32 KB

    hipMemsetAsync(node, 0, (size_t)N * 1024 * sizeof(float), stream);

    int npack = N_WVQ + N_W2A + N_W2B + N_W2C + N_W1I;
    hipLaunchKernelGGL(k_pack, dim3((npack + 255) / 256), dim3(256), 0, stream,
                       Wv1, Wv2, W2a, W2b, W2c, W1, WvQ, W2aI, W2bI, W2cI, W1I);

    dim3 blkA(256), grdA((unsigned)(((size_t)E * 64 + 255) / 256));
    hipLaunchKernelGGL(k_edge_pre, grdA, blkA, 0, stream,
                       vectors, x, senders, W1I, node, E, pack);

    float* xout = (float*)d_out;
    float* vout = xout + (size_t)E * 64;
    hipLaunchKernelGGL(k_edge_main, dim3((unsigned)E), dim3(64), 0, stream,
                       vectors, x, V, senders, node, WvQ,
                       W2aI, W2bI, W2cI, xout, vout, E, pack);
}